// Round 5
// baseline (977.600 us; speedup 1.0000x reference)
//
#include <hip/hip_runtime.h>
#include <hip/hip_bf16.h>
#include <math.h>

#define S 1024
#define NLAYER 4

typedef __bf16 bf16x8 __attribute__((ext_vector_type(8)));
typedef float floatx4 __attribute__((ext_vector_type(4)));

__device__ __forceinline__ float wave_sum(float v) {
  #pragma unroll
  for (int off = 32; off > 0; off >>= 1) v += __shfl_xor(v, off, 64);
  return v;
}

// ---------------- embed: h = [x, tf] @ Wp + bp (fp32) ----------------
__global__ __launch_bounds__(256) void embed_kernel(
    const float* __restrict__ x, const float* __restrict__ tf,
    const float* __restrict__ Wp, const float* __restrict__ bp,
    float* __restrict__ h) {
  int row = blockIdx.x;
  int n = threadIdx.x;
  float xv = x[row];
  const float* t4 = tf + (size_t)row * 4;
  float acc = bp[n] + xv * Wp[n];
  acc += t4[0] * Wp[256 + n];
  acc += t4[1] * Wp[512 + n];
  acc += t4[2] * Wp[768 + n];
  acc += t4[3] * Wp[1024 + n];
  h[(size_t)row * 256 + n] = acc;
}

// ---------------- weight transpose+cast: W[K][N] f32 -> WT[N][K] bf16 ----------------
// Wq/Wk land in one combined WqkT[l][1024][512] (rows 0-511 = Q, 512-1023 = K).
__global__ __launch_bounds__(256) void wtrans_kernel(
    const float* __restrict__ Wup, const float* __restrict__ Wq,
    const float* __restrict__ Wk, const float* __restrict__ Wv,
    const float* __restrict__ Wdown,
    __bf16* __restrict__ WupT, __bf16* __restrict__ WqkT,
    __bf16* __restrict__ WvT, __bf16* __restrict__ WdownT) {
  __shared__ float T[32][33];
  int bid = blockIdx.x;
  int layer = bid / 1152, rr = bid % 1152;
  const float* src; __bf16* dst; int K, N, tile;
  if (rr < 256)       { src = Wup   + layer * 262144; dst = WupT  + layer * 262144;          K = 256; N = 1024; tile = rr; }
  else if (rr < 512)  { src = Wq    + layer * 262144; dst = WqkT  + layer * 524288;          K = 512; N = 512;  tile = rr - 256; }
  else if (rr < 768)  { src = Wk    + layer * 262144; dst = WqkT  + layer * 524288 + 262144; K = 512; N = 512;  tile = rr - 512; }
  else if (rr < 1024) { src = Wv    + layer * 262144; dst = WvT   + layer * 262144;          K = 512; N = 512;  tile = rr - 768; }
  else                { src = Wdown + layer * 131072; dst = WdownT + layer * 131072;         K = 512; N = 256;  tile = rr - 1024; }
  int ntn = N >> 5;
  int tk = tile / ntn, tn = tile % ntn;
  int tid = threadIdx.x;
  int r = tid >> 3, c4 = (tid & 7) * 4;
  float4 v = *(const float4*)(src + (size_t)(tk * 32 + r) * N + tn * 32 + c4);
  T[c4 + 0][r] = v.x; T[c4 + 1][r] = v.y; T[c4 + 2][r] = v.z; T[c4 + 3][r] = v.w;
  __syncthreads();
  __bf16 o[4];
  #pragma unroll
  for (int j = 0; j < 4; ++j) o[j] = (__bf16)T[r][c4 + j];
  *(uint2*)(dst + (size_t)(tn * 32 + r) * K + tk * 32 + c4) = *(uint2*)o;
}

// ---------------- Wg precompute: Wg1 = Wq@Wif_q + Wk@Wif_k ; Wg2 = Wv@Wif_v ----------------
// wg[l][0][512][8] = Wg1, wg[l][1][512][8] = Wg2  (f32)
__global__ __launch_bounds__(256) void wgprep_kernel(
    const float* __restrict__ Wq, const float* __restrict__ Wk,
    const float* __restrict__ Wv, const float* __restrict__ Wif,
    float* __restrict__ wg) {
  int bid = blockIdx.x;          // 64 blocks
  int l = bid >> 4, part = bid & 15;
  int sel = part >> 3, j = part & 7;
  const float* wif = Wif + (size_t)l * 1536 * 8;
  #pragma unroll
  for (int half = 0; half < 2; ++half) {
    int k = threadIdx.x + half * 256;
    float acc = 0.f;
    if (sel == 0) {
      const float* q = Wq + (size_t)l * 262144 + (size_t)k * 512;
      const float* kk = Wk + (size_t)l * 262144 + (size_t)k * 512;
      for (int n = 0; n < 512; ++n) {
        acc += q[n] * wif[n * 8 + j];
        acc += kk[n] * wif[(512 + n) * 8 + j];
      }
    } else {
      const float* v = Wv + (size_t)l * 262144 + (size_t)k * 512;
      for (int n = 0; n < 512; ++n) acc += v[n] * wif[(1024 + n) * 8 + j];
    }
    wg[(size_t)l * 8192 + sel * 4096 + k * 8 + j] = acc;
  }
}

// ---------------- LayerNorm over 256, fp32 in -> bf16 out ----------------
__global__ __launch_bounds__(256) void ln256_kernel(
    const float* __restrict__ x, const float* __restrict__ g,
    const float* __restrict__ b, __bf16* __restrict__ y) {
  int row = blockIdx.x, tid = threadIdx.x;
  __shared__ float red[4];
  float v = x[(size_t)row * 256 + tid];
  float s = wave_sum(v);
  int wid = tid >> 6, lane = tid & 63;
  if (lane == 0) red[wid] = s;
  __syncthreads();
  float mu = (red[0] + red[1] + red[2] + red[3]) * (1.f / 256.f);
  __syncthreads();
  float d = v - mu;
  float s2 = wave_sum(d * d);
  if (lane == 0) red[wid] = s2;
  __syncthreads();
  float var = (red[0] + red[1] + red[2] + red[3]) * (1.f / 256.f);
  float rs = rsqrtf(var + 1e-5f);
  y[(size_t)row * 256 + tid] = (__bf16)(d * rs * g[tid] + b[tid]);
}

// ---------------- bf16 MFMA GEMM: C[M,N] = A[M,K] @ BT[N,K]^T (+bias) ----------------
// MODE 0: f32 out (+ACC adds prev), MODE 1: bf16 row-major, MODE 2: bf16 scattered into vT.
template <int MODE, int ACC>
__global__ __launch_bounds__(256) void hgemm(
    const __bf16* __restrict__ A, int lda,
    const __bf16* __restrict__ BT, int Kdim,
    const float* __restrict__ bias,
    void* __restrict__ Cout, int ldc) {
  __shared__ __bf16 As[128][40];
  __shared__ __bf16 Bs[128][40];
  int tid = threadIdx.x;
  int bn = blockIdx.x * 128, bm = blockIdx.y * 128;
  int wid = tid >> 6, lane = tid & 63;
  int wr = wid >> 1, wc = wid & 1;
  int lg = lane >> 4, li = lane & 15;
  floatx4 acc[4][4];
  #pragma unroll
  for (int i = 0; i < 4; ++i)
    #pragma unroll
    for (int j = 0; j < 4; ++j) acc[i][j] = (floatx4)(0.f);

  int arow = tid >> 2, aseg = tid & 3;
  for (int k0 = 0; k0 < Kdim; k0 += 32) {
    __syncthreads();
    *(bf16x8*)&As[arow][aseg * 8] =
        *(const bf16x8*)(A + (size_t)(bm + arow) * lda + k0 + aseg * 8);
    *(bf16x8*)&As[arow + 64][aseg * 8] =
        *(const bf16x8*)(A + (size_t)(bm + arow + 64) * lda + k0 + aseg * 8);
    *(bf16x8*)&Bs[arow][aseg * 8] =
        *(const bf16x8*)(BT + (size_t)(bn + arow) * Kdim + k0 + aseg * 8);
    *(bf16x8*)&Bs[arow + 64][aseg * 8] =
        *(const bf16x8*)(BT + (size_t)(bn + arow + 64) * Kdim + k0 + aseg * 8);
    __syncthreads();
    bf16x8 af[4], bfr[4];
    #pragma unroll
    for (int mi = 0; mi < 4; ++mi)
      af[mi] = *(const bf16x8*)&As[wr * 64 + mi * 16 + li][lg * 8];
    #pragma unroll
    for (int ni = 0; ni < 4; ++ni)
      bfr[ni] = *(const bf16x8*)&Bs[wc * 64 + ni * 16 + li][lg * 8];
    #pragma unroll
    for (int mi = 0; mi < 4; ++mi)
      #pragma unroll
      for (int ni = 0; ni < 4; ++ni)
        acc[mi][ni] = __builtin_amdgcn_mfma_f32_16x16x32_bf16(af[mi], bfr[ni], acc[mi][ni], 0, 0, 0);
  }
  #pragma unroll
  for (int mi = 0; mi < 4; ++mi) {
    int row = bm + wr * 64 + mi * 16 + lg * 4;
    #pragma unroll
    for (int ni = 0; ni < 4; ++ni) {
      int col = bn + wc * 64 + ni * 16 + li;
      if (MODE == 2) {
        // scatter into vT[bh][128][1024]: bh=(row>>10)*4 + col>>7, d=col&127, t=row&1023
        __bf16 o4[4];
        #pragma unroll
        for (int r = 0; r < 4; ++r) o4[r] = (__bf16)acc[mi][ni][r];
        __bf16* vt = (__bf16*)Cout;
        size_t off = ((size_t)((row >> 10) * 4 + (col >> 7)) * 128 + (col & 127)) * 1024 + (row & 1023);
        *(uint2*)(vt + off) = *(uint2*)o4;
      } else {
        float bz = bias ? bias[col] : 0.f;
        if (MODE == 1) {
          __bf16* C = (__bf16*)Cout;
          #pragma unroll
          for (int r = 0; r < 4; ++r)
            C[(size_t)(row + r) * ldc + col] = (__bf16)(acc[mi][ni][r] + bz);
        } else {
          float* C = (float*)Cout;
          #pragma unroll
          for (int r = 0; r < 4; ++r) {
            float v = acc[mi][ni][r] + bz;
            if (ACC) v += C[(size_t)(row + r) * ldc + col];
            C[(size_t)(row + r) * ldc + col] = v;
          }
        }
      }
    }
  }
}

// ---------------- causal depthwise conv (K=4) + SiLU, vectorized 8 ch/thread ----------------
__global__ __launch_bounds__(256) void conv_silu_kernel(
    const __bf16* __restrict__ up, const float* __restrict__ cw,
    const float* __restrict__ cb, __bf16* __restrict__ xc) {
  int idx = blockIdx.x * 256 + threadIdx.x;  // 8192*64
  int row = idx >> 6;
  int c8 = (idx & 63) * 8;
  int t = row & (S - 1);
  float acc[8];
  *(float4*)&acc[0] = *(const float4*)(cb + c8);
  *(float4*)&acc[4] = *(const float4*)(cb + c8 + 4);
  #pragma unroll
  for (int j = 0; j < 4; ++j) {
    int tt = t - 3 + j;
    if (tt >= 0) {
      bf16x8 xv = *(const bf16x8*)(up + (size_t)(row - 3 + j) * 1024 + c8);
      float4 w0 = *(const float4*)(cw + j * 512 + c8);
      float4 w1 = *(const float4*)(cw + j * 512 + c8 + 4);
      acc[0] += w0.x * (float)xv[0]; acc[1] += w0.y * (float)xv[1];
      acc[2] += w0.z * (float)xv[2]; acc[3] += w0.w * (float)xv[3];
      acc[4] += w1.x * (float)xv[4]; acc[5] += w1.y * (float)xv[5];
      acc[6] += w1.z * (float)xv[6]; acc[7] += w1.w * (float)xv[7];
    }
  }
  bf16x8 o;
  #pragma unroll
  for (int m = 0; m < 8; ++m) {
    float sg = 1.f / (1.f + __expf(-acc[m]));
    o[m] = (__bf16)(acc[m] * sg);
  }
  *(bf16x8*)(xc + (size_t)row * 512 + c8) = o;
}

// ---------------- gates = xc@Wg1 + xm@Wg2 + bif  (wave per row) ----------------
__global__ __launch_bounds__(256) void gates_kernel(
    const __bf16* __restrict__ xc, const __bf16* __restrict__ up,
    const float* __restrict__ wg, const float* __restrict__ bif,
    float* __restrict__ gates) {
  int tid = threadIdx.x;
  int wv = tid >> 6, lane = tid & 63;
  int row = blockIdx.x * 4 + wv;
  bf16x8 xcv = *(const bf16x8*)(xc + (size_t)row * 512 + lane * 8);
  bf16x8 xmv = *(const bf16x8*)(up + (size_t)row * 1024 + lane * 8);
  const float* w1 = wg + (size_t)(lane * 8) * 8;         // Wg1[k][8]
  const float* w2 = wg + 4096 + (size_t)(lane * 8) * 8;  // Wg2[k][8]
  float part[8] = {0, 0, 0, 0, 0, 0, 0, 0};
  #pragma unroll
  for (int m = 0; m < 8; ++m) {
    float xcf = (float)xcv[m], xmf = (float)xmv[m];
    const float* a = w1 + m * 8;
    const float* b = w2 + m * 8;
    #pragma unroll
    for (int j = 0; j < 8; ++j) part[j] += xcf * a[j] + xmf * b[j];
  }
  #pragma unroll
  for (int j = 0; j < 8; ++j) part[j] = wave_sum(part[j]);
  if (lane < 8) gates[(size_t)row * 8 + lane] = part[lane] + bif[lane];
  // note: wave_sum leaves the full sum in every lane; lane j writes part[j]? No —
  // each lane has all 8 sums; lane j writes its own j-th entry.
}

// ---------------- per-(b,h) gate scan: one wave, lane-serial 16 + shuffle scan ----------------
__global__ __launch_bounds__(64) void scan_kernel(
    const float* __restrict__ gates, float* __restrict__ gout,
    float* __restrict__ Mout, float* __restrict__ NFout) {
  int bh = blockIdx.x;
  int bb = bh >> 2, hh = bh & 3;
  int lane = threadIdx.x;
  float ip[16], pf[16];
  #pragma unroll
  for (int i = 0; i < 16; ++i) {
    int t = lane * 16 + i;
    const float* grow = gates + ((size_t)(bb * S + t)) * 8;
    ip[i] = grow[hh];
    float fp = grow[4 + hh];
    float lf = fminf(fp, 0.f) - log1pf(__expf(-fabsf(fp)));
    pf[i] = (i == 0) ? lf : pf[i - 1] + lf;  // lane-local inclusive prefix sum
  }
  float T = pf[15];
  float inc = T;
  #pragma unroll
  for (int off = 1; off < 64; off <<= 1) {
    float v = __shfl_up(inc, off, 64);
    if (lane >= off) inc += v;
  }
  float excl = inc - T;
  float F[16], g[16], pm[16];
  #pragma unroll
  for (int i = 0; i < 16; ++i) {
    F[i] = excl + pf[i];
    g[i] = ip[i] - F[i];
    pm[i] = (i == 0) ? g[0] : fmaxf(pm[i - 1], g[i]);
  }
  float Mx = pm[15];
  float incm = Mx;
  #pragma unroll
  for (int off = 1; off < 64; off <<= 1) {
    float v = __shfl_up(incm, off, 64);
    if (lane >= off) incm = fmaxf(incm, v);
  }
  float em = __shfl_up(incm, 1, 64);
  if (lane == 0) em = -3.4e38f;
  #pragma unroll
  for (int i = 0; i < 16; ++i) {
    int t = lane * 16 + i;
    size_t o = (size_t)bh * S + t;
    float M = fmaxf(em, pm[i]);
    gout[o] = g[i];
    Mout[o] = M;
    NFout[o] = __expf(-F[i] - M);
  }
}

// ---------------- MFMA mLSTM attention, paired q-tiles + LDS staging ----------------
// qk: [B*S][1024] bf16, q cols 0-511, k cols 512-1023. vT: [bh][128][1024].
__global__ __launch_bounds__(256, 1) void attn_kernel(
    const __bf16* __restrict__ qk, const __bf16* __restrict__ vT,
    const float* __restrict__ gbuf, const float* __restrict__ Mbuf,
    const float* __restrict__ NFbuf, float* __restrict__ hatt) {
  __shared__ __bf16 Ks[64][136];
  __shared__ __bf16 Vs[128][72];
  __shared__ __bf16 plds[4][2][16][72];
  __shared__ float gls[64];
  int px = blockIdx.x, bh = blockIdx.y;
  int tqA = px, tqB = 15 - px;
  int bb = bh >> 2, hh = bh & 3;
  int tid = threadIdx.x;
  int wv = tid >> 6, lane = tid & 63;
  int lg = lane >> 4, li = lane & 15;
  int tbA = tqA * 64 + wv * 16;
  int tbB = tqB * 64 + wv * 16;
  const float scale = 0.08838834764831845f;

  bf16x8 aqA[4], aqB[4];
  {
    const __bf16* qpA = qk + ((size_t)(bb * S + tbA + li)) * 1024 + hh * 128 + lg * 8;
    const __bf16* qpB = qk + ((size_t)(bb * S + tbB + li)) * 1024 + hh * 128 + lg * 8;
    #pragma unroll
    for (int cd = 0; cd < 4; ++cd) {
      aqA[cd] = *(const bf16x8*)(qpA + cd * 32);
      aqB[cd] = *(const bf16x8*)(qpB + cd * 32);
    }
  }
  float mlA[4], nfA[4], mlB[4], nfB[4];
  #pragma unroll
  for (int r = 0; r < 4; ++r) {
    mlA[r] = Mbuf[(size_t)bh * S + tbA + lg * 4 + r];
    nfA[r] = NFbuf[(size_t)bh * S + tbA + lg * 4 + r];
    mlB[r] = Mbuf[(size_t)bh * S + tbB + lg * 4 + r];
    nfB[r] = NFbuf[(size_t)bh * S + tbB + lg * 4 + r];
  }

  floatx4 oA[8], oB[8];
  #pragma unroll
  for (int df = 0; df < 8; ++df) { oA[df] = (floatx4)(0.f); oB[df] = (floatx4)(0.f); }
  float rsA[4] = {0, 0, 0, 0}, rsB[4] = {0, 0, 0, 0};

  int krow = tid >> 3, kcol = tid & 7;
  bf16x8 kreg[4], vreg[4];
  float greg = 0.f;
  auto preload = [&](int st) {
    int s0 = st * 64;
    const __bf16* kp = qk + ((size_t)(bb * S + s0 + krow)) * 1024 + 512 + hh * 128;
    kreg[0] = *(const bf16x8*)(kp + kcol * 8);
    kreg[1] = *(const bf16x8*)(kp + (size_t)32 * 1024 + kcol * 8);
    kreg[2] = *(const bf16x8*)(kp + 64 + kcol * 8);
    kreg[3] = *(const bf16x8*)(kp + (size_t)32 * 1024 + 64 + kcol * 8);
    #pragma unroll
    for (int i = 0; i < 4; ++i)
      vreg[i] = *(const bf16x8*)(vT + ((size_t)(bh * 128 + krow + i * 32)) * 1024 + s0 + kcol * 8);
    if (tid < 64) greg = gbuf[(size_t)bh * S + s0 + tid];
  };
  preload(0);

  for (int st = 0; st <= tqB; ++st) {
    __syncthreads();
    *(bf16x8*)&Ks[krow][kcol * 8] = kreg[0];
    *(bf16x8*)&Ks[krow + 32][kcol * 8] = kreg[1];
    *(bf16x8*)&Ks[krow][64 + kcol * 8] = kreg[2];
    *(bf16x8*)&Ks[krow + 32][64 + kcol * 8] = kreg[3];
    #pragma unroll
    for (int i = 0; i < 4; ++i) *(bf16x8*)&Vs[krow + i * 32][kcol * 8] = vreg[i];
    if (tid < 64) gls[tid] = greg;
    __syncthreads();
    if (st < tqB) preload(st + 1);

    int s0 = st * 64;
    bool actA = (st <= tqA);
    #pragma unroll
    for (int ns = 0; ns < 4; ++ns) {
      bf16x8 bk0 = *(const bf16x8*)&Ks[ns * 16 + li][lg * 8];
      bf16x8 bk1 = *(const bf16x8*)&Ks[ns * 16 + li][32 + lg * 8];
      bf16x8 bk2 = *(const bf16x8*)&Ks[ns * 16 + li][64 + lg * 8];
      bf16x8 bk3 = *(const bf16x8*)&Ks[ns * 16 + li][96 + lg * 8];
      int s = s0 + ns * 16 + li;
      float gv = gls[ns * 16 + li];
      if (actA) {
        floatx4 pa = (floatx4)(0.f);
        pa = __builtin_amdgcn_mfma_f32_16x16x32_bf16(aqA[0], bk0, pa, 0, 0, 0);
        pa = __builtin_amdgcn_mfma_f32_16x16x32_bf16(aqA[1], bk1, pa, 0, 0, 0);
        pa = __builtin_amdgcn_mfma_f32_16x16x32_bf16(aqA[2], bk2, pa, 0, 0, 0);
        pa = __builtin_amdgcn_mfma_f32_16x16x32_bf16(aqA[3], bk3, pa, 0, 0, 0);
        #pragma unroll
        for (int r = 0; r < 4; ++r) {
          int t = tbA + lg * 4 + r;
          float val = pa[r] * scale * __expf(gv - mlA[r]);
          float w = (s <= t) ? val : 0.f;
          rsA[r] += w;
          plds[wv][0][lg * 4 + r][ns * 16 + li] = (__bf16)w;
        }
      }
      {
        floatx4 pb = (floatx4)(0.f);
        pb = __builtin_amdgcn_mfma_f32_16x16x32_bf16(aqB[0], bk0, pb, 0, 0, 0);
        pb = __builtin_amdgcn_mfma_f32_16x16x32_bf16(aqB[1], bk1, pb, 0, 0, 0);
        pb = __builtin_amdgcn_mfma_f32_16x16x32_bf16(aqB[2], bk2, pb, 0, 0, 0);
        pb = __builtin_amdgcn_mfma_f32_16x16x32_bf16(aqB[3], bk3, pb, 0, 0, 0);
        #pragma unroll
        for (int r = 0; r < 4; ++r) {
          int t = tbB + lg * 4 + r;
          float val = pb[r] * scale * __expf(gv - mlB[r]);
          float w = (s <= t) ? val : 0.f;
          rsB[r] += w;
          plds[wv][1][lg * 4 + r][ns * 16 + li] = (__bf16)w;
        }
      }
    }
    bf16x8 apA0, apA1, apB0, apB1;
    if (actA) {
      apA0 = *(const bf16x8*)&plds[wv][0][li][lg * 8];
      apA1 = *(const bf16x8*)&plds[wv][0][li][32 + lg * 8];
    }
    apB0 = *(const bf16x8*)&plds[wv][1][li][lg * 8];
    apB1 = *(const bf16x8*)&plds[wv][1][li][32 + lg * 8];
    #pragma unroll
    for (int df = 0; df < 8; ++df) {
      bf16x8 bv0 = *(const bf16x8*)&Vs[df * 16 + li][lg * 8];
      bf16x8 bv1 = *(const bf16x8*)&Vs[df * 16 + li][32 + lg * 8];
      if (actA) {
        oA[df] = __builtin_amdgcn_mfma_f32_16x16x32_bf16(apA0, bv0, oA[df], 0, 0, 0);
        oA[df] = __builtin_amdgcn_mfma_f32_16x16x32_bf16(apA1, bv1, oA[df], 0, 0, 0);
      }
      oB[df] = __builtin_amdgcn_mfma_f32_16x16x32_bf16(apB0, bv0, oB[df], 0, 0, 0);
      oB[df] = __builtin_amdgcn_mfma_f32_16x16x32_bf16(apB1, bv1, oB[df], 0, 0, 0);
    }
  }
  #pragma unroll
  for (int r = 0; r < 4; ++r) {
    float a = rsA[r], b = rsB[r];
    a += __shfl_xor(a, 1, 64); a += __shfl_xor(a, 2, 64);
    a += __shfl_xor(a, 4, 64); a += __shfl_xor(a, 8, 64);
    b += __shfl_xor(b, 1, 64); b += __shfl_xor(b, 2, 64);
    b += __shfl_xor(b, 4, 64); b += __shfl_xor(b, 8, 64);
    rsA[r] = a; rsB[r] = b;
  }
  #pragma unroll
  for (int r = 0; r < 4; ++r) {
    float invA = 1.f / (fmaxf(fabsf(rsA[r]), nfA[r]) + 1e-6f);
    float invB = 1.f / (fmaxf(fabsf(rsB[r]), nfB[r]) + 1e-6f);
    float* obA = hatt + ((size_t)(bb * S + tbA + lg * 4 + r)) * 512 + hh * 128 + li;
    float* obB = hatt + ((size_t)(bb * S + tbB + lg * 4 + r)) * 512 + hh * 128 + li;
    #pragma unroll
    for (int df = 0; df < 8; ++df) {
      obA[df * 16] = oA[df][r] * invA;
      obB[df * 16] = oB[df][r] * invB;
    }
  }
}

// ---------------- GroupNorm + skip*xc + *silu(z): hatt f32 -> hd bf16 ----------------
__global__ __launch_bounds__(512) void gn_kernel(
    const float* __restrict__ hatt, const float* __restrict__ gg,
    const float* __restrict__ gb, const float* __restrict__ skip,
    const __bf16* __restrict__ xc, const __bf16* __restrict__ up,
    __bf16* __restrict__ hd) {
  int row = blockIdx.x, tid = threadIdx.x;
  int head = tid >> 7;
  __shared__ float red[8];
  float v = hatt[(size_t)row * 512 + tid];
  float s = wave_sum(v);
  int wid = tid >> 6, lane = tid & 63;
  if (lane == 0) red[wid] = s;
  __syncthreads();
  float mu = (red[head * 2] + red[head * 2 + 1]) * (1.f / 128.f);
  __syncthreads();
  float d = v - mu;
  float s2 = wave_sum(d * d);
  if (lane == 0) red[wid] = s2;
  __syncthreads();
  float var = (red[head * 2] + red[head * 2 + 1]) * (1.f / 128.f);
  float rsq = rsqrtf(var + 1e-5f);
  float ln = d * rsq * gg[tid] + gb[tid];
  float val = ln + skip[tid] * (float)xc[(size_t)row * 512 + tid];
  float z = (float)up[(size_t)row * 1024 + 512 + tid];
  float sg = 1.f / (1.f + expf(-z));
  hd[(size_t)row * 512 + tid] = (__bf16)(val * (z * sg));
}

// ---------------- final LN + head ----------------
__global__ __launch_bounds__(256) void final_kernel(
    const float* __restrict__ h, const float* __restrict__ g,
    const float* __restrict__ b, const float* __restrict__ Wf,
    const float* __restrict__ bf, float* __restrict__ out) {
  int bb = blockIdx.x, tid = threadIdx.x;
  size_t row = (size_t)(bb * S + S - 1) * 256;
  __shared__ float red[4];
  float v = h[row + tid];
  float s = wave_sum(v);
  int wid = tid >> 6, lane = tid & 63;
  if (lane == 0) red[wid] = s;
  __syncthreads();
  float mu = (red[0] + red[1] + red[2] + red[3]) * (1.f / 256.f);
  __syncthreads();
  float d = v - mu;
  float s2 = wave_sum(d * d);
  if (lane == 0) red[wid] = s2;
  __syncthreads();
  float var = (red[0] + red[1] + red[2] + red[3]) * (1.f / 256.f);
  float rs = rsqrtf(var + 1e-5f);
  float ln = d * rs * g[tid] + b[tid];
  float p = ln * Wf[tid];
  float psum = wave_sum(p);
  __syncthreads();
  if (lane == 0) red[wid] = psum;
  __syncthreads();
  if (tid == 0) out[bb] = red[0] + red[1] + red[2] + red[3] + bf[0];
}

extern "C" void kernel_launch(void* const* d_in, const int* in_sizes, int n_in,
                              void* d_out, int out_size, void* d_ws, size_t ws_size,
                              hipStream_t stream) {
  const float* x      = (const float*)d_in[0];
  const float* tf     = (const float*)d_in[1];
  const float* Wp     = (const float*)d_in[2];
  const float* bp     = (const float*)d_in[3];
  const float* ln_g   = (const float*)d_in[4];
  const float* ln_b   = (const float*)d_in[5];
  const float* Wup    = (const float*)d_in[6];
  const float* bup    = (const float*)d_in[7];
  const float* conv_w = (const float*)d_in[8];
  const float* conv_b = (const float*)d_in[9];
  const float* Wq     = (const float*)d_in[10];
  const float* Wk     = (const float*)d_in[11];
  const float* Wv     = (const float*)d_in[12];
  const float* Wif    = (const float*)d_in[13];
  const float* bif    = (const float*)d_in[14];
  const float* gn_g   = (const float*)d_in[15];
  const float* gn_b   = (const float*)d_in[16];
  const float* skip   = (const float*)d_in[17];
  const float* Wdown  = (const float*)d_in[18];
  const float* bdown  = (const float*)d_in[19];
  const float* lnf_g  = (const float*)d_in[20];
  const float* lnf_b  = (const float*)d_in[21];
  const float* Wf     = (const float*)d_in[22];
  const float* bf     = (const float*)d_in[23];
  float* out = (float*)d_out;

  float* h     = (float*)d_ws;              // 2,097,152 f32
  float* hatt  = h + 2097152;               // 4,194,304 f32
  float* gates = hatt + 4194304;            // 65,536 f32
  float* gbuf  = gates + 65536;             // 32,768
  float* Mbuf  = gbuf + 32768;              // 32,768
  float* NFbuf = Mbuf + 32768;              // 32,768
  float* wgbuf = NFbuf + 32768;             // 32,768 (4 layers x 2 x 512 x 8)
  __bf16* hn   = (__bf16*)(wgbuf + 32768);  // 2,097,152 bf16
  __bf16* up   = hn + 2097152;              // 8,388,608
  __bf16* xc   = up + 8388608;              // 4,194,304
  __bf16* qk   = xc + 4194304;              // 8,388,608
  __bf16* vT   = qk + 8388608;              // 4,194,304
  __bf16* hd   = vT + 4194304;              // 4,194,304
  __bf16* WupT   = hd + 4194304;            // 1,048,576
  __bf16* WqkT   = WupT + 1048576;          // 2,097,152
  __bf16* WvT    = WqkT + 2097152;          // 1,048,576
  __bf16* WdownT = WvT + 1048576;           // 524,288
  // ~98 MB total

  wtrans_kernel<<<4608, 256, 0, stream>>>(Wup, Wq, Wk, Wv, Wdown,
                                          WupT, WqkT, WvT, WdownT);
  wgprep_kernel<<<64, 256, 0, stream>>>(Wq, Wk, Wv, Wif, wgbuf);
  embed_kernel<<<8192, 256, 0, stream>>>(x, tf, Wp, bp, h);
  for (int l = 0; l < NLAYER; ++l) {
    ln256_kernel<<<8192, 256, 0, stream>>>(h, ln_g + l * 256, ln_b + l * 256, hn);
    hgemm<1, 0><<<dim3(8, 64), 256, 0, stream>>>(
        hn, 256, WupT + (size_t)l * 262144, 256, bup + l * 1024, up, 1024);
    conv_silu_kernel<<<2048, 256, 0, stream>>>(up, conv_w + l * 2048, conv_b + l * 512, xc);
    hgemm<1, 0><<<dim3(8, 64), 256, 0, stream>>>(
        xc, 512, WqkT + (size_t)l * 524288, 512, nullptr, qk, 1024);
    hgemm<2, 0><<<dim3(4, 64), 256, 0, stream>>>(
        up, 1024, WvT + (size_t)l * 262144, 512, nullptr, vT, 0);
    gates_kernel<<<2048, 256, 0, stream>>>(xc, up, wgbuf + l * 8192, bif + l * 8, gates);
    scan_kernel<<<32, 64, 0, stream>>>(gates, gbuf, Mbuf, NFbuf);
    attn_kernel<<<dim3(8, 32), 256, 0, stream>>>(qk, vT, gbuf, Mbuf, NFbuf, hatt);
    gn_kernel<<<8192, 512, 0, stream>>>(hatt, gn_g + l * 512, gn_b + l * 512,
                                        skip + l * 512, xc, up, hd);
    hgemm<0, 1><<<dim3(2, 64), 256, 0, stream>>>(
        hd, 512, WdownT + (size_t)l * 131072, 512, bdown + l * 256, h, 256);
  }
  final_kernel<<<8, 256, 0, stream>>>(h, lnf_g, lnf_b, Wf, bf, out);
}

// Round 6
// 854.123 us; speedup vs baseline: 1.1446x; 1.1446x over previous
//
#include <hip/hip_runtime.h>
#include <hip/hip_bf16.h>
#include <math.h>

#define S 1024
#define NLAYER 4

typedef __bf16 bf16x8 __attribute__((ext_vector_type(8)));
typedef float floatx4 __attribute__((ext_vector_type(4)));

__device__ __forceinline__ float wave_sum(float v) {
  #pragma unroll
  for (int off = 32; off > 0; off >>= 1) v += __shfl_xor(v, off, 64);
  return v;
}

// ---------------- embed: h = [x, tf] @ Wp + bp (fp32) ----------------
__global__ __launch_bounds__(256) void embed_kernel(
    const float* __restrict__ x, const float* __restrict__ tf,
    const float* __restrict__ Wp, const float* __restrict__ bp,
    float* __restrict__ h) {
  int row = blockIdx.x;
  int n = threadIdx.x;
  float xv = x[row];
  const float* t4 = tf + (size_t)row * 4;
  float acc = bp[n] + xv * Wp[n];
  acc += t4[0] * Wp[256 + n];
  acc += t4[1] * Wp[512 + n];
  acc += t4[2] * Wp[768 + n];
  acc += t4[3] * Wp[1024 + n];
  h[(size_t)row * 256 + n] = acc;
}

// ---------------- weight transpose+cast: W[K][N] f32 -> WT[N][K] bf16 ----------------
// Wq/Wk land in one combined WqkT[l][1024][512] (rows 0-511 = Q, 512-1023 = K).
__global__ __launch_bounds__(256) void wtrans_kernel(
    const float* __restrict__ Wup, const float* __restrict__ Wq,
    const float* __restrict__ Wk, const float* __restrict__ Wv,
    const float* __restrict__ Wdown,
    __bf16* __restrict__ WupT, __bf16* __restrict__ WqkT,
    __bf16* __restrict__ WvT, __bf16* __restrict__ WdownT) {
  __shared__ float T[32][33];
  int bid = blockIdx.x;
  int layer = bid / 1152, rr = bid % 1152;
  const float* src; __bf16* dst; int K, N, tile;
  if (rr < 256)       { src = Wup   + layer * 262144; dst = WupT  + layer * 262144;          K = 256; N = 1024; tile = rr; }
  else if (rr < 512)  { src = Wq    + layer * 262144; dst = WqkT  + layer * 524288;          K = 512; N = 512;  tile = rr - 256; }
  else if (rr < 768)  { src = Wk    + layer * 262144; dst = WqkT  + layer * 524288 + 262144; K = 512; N = 512;  tile = rr - 512; }
  else if (rr < 1024) { src = Wv    + layer * 262144; dst = WvT   + layer * 262144;          K = 512; N = 512;  tile = rr - 768; }
  else                { src = Wdown + layer * 131072; dst = WdownT + layer * 131072;         K = 512; N = 256;  tile = rr - 1024; }
  int ntn = N >> 5;
  int tk = tile / ntn, tn = tile % ntn;
  int tid = threadIdx.x;
  int r = tid >> 3, c4 = (tid & 7) * 4;
  float4 v = *(const float4*)(src + (size_t)(tk * 32 + r) * N + tn * 32 + c4);
  T[c4 + 0][r] = v.x; T[c4 + 1][r] = v.y; T[c4 + 2][r] = v.z; T[c4 + 3][r] = v.w;
  __syncthreads();
  __bf16 o[4];
  #pragma unroll
  for (int j = 0; j < 4; ++j) o[j] = (__bf16)T[r][c4 + j];
  *(uint2*)(dst + (size_t)(tn * 32 + r) * K + tk * 32 + c4) = *(uint2*)o;
}

// ---------------- Wg precompute: Wg1 = Wq@Wif_q + Wk@Wif_k ; Wg2 = Wv@Wif_v ----------------
// wg[l][0][512][8] = Wg1, wg[l][1][512][8] = Wg2  (f32)
// Wave per output row k: lanes stride n (coalesced row reads), 8 partials, wave-reduce.
__global__ __launch_bounds__(256) void wgprep_kernel(
    const float* __restrict__ Wq, const float* __restrict__ Wk,
    const float* __restrict__ Wv, const float* __restrict__ Wif,
    float* __restrict__ wg) {
  int bid = blockIdx.x;      // 1024 blocks: 256 per layer
  int l = bid >> 8;
  int rem = bid & 255;
  int sel = rem >> 7;        // 0: Wg1, 1: Wg2
  int kg = rem & 127;        // group of 4 k-rows
  int tid = threadIdx.x;
  int wv = tid >> 6, lane = tid & 63;
  int k = kg * 4 + wv;
  const float* wif = Wif + (size_t)l * 1536 * 8;
  float part[8] = {0, 0, 0, 0, 0, 0, 0, 0};
  if (sel == 0) {
    const float* qr = Wq + (size_t)l * 262144 + (size_t)k * 512;
    const float* kr = Wk + (size_t)l * 262144 + (size_t)k * 512;
    #pragma unroll
    for (int i = 0; i < 8; ++i) {
      int n = lane + i * 64;
      float qv = qr[n], kv = kr[n];
      const float* wq8 = wif + (size_t)n * 8;
      const float* wk8 = wif + (size_t)(512 + n) * 8;
      #pragma unroll
      for (int j = 0; j < 8; ++j) part[j] += qv * wq8[j] + kv * wk8[j];
    }
  } else {
    const float* vr = Wv + (size_t)l * 262144 + (size_t)k * 512;
    #pragma unroll
    for (int i = 0; i < 8; ++i) {
      int n = lane + i * 64;
      float vv = vr[n];
      const float* wv8 = wif + (size_t)(1024 + n) * 8;
      #pragma unroll
      for (int j = 0; j < 8; ++j) part[j] += vv * wv8[j];
    }
  }
  #pragma unroll
  for (int j = 0; j < 8; ++j) part[j] = wave_sum(part[j]);
  if (lane < 8) wg[(size_t)l * 8192 + sel * 4096 + (size_t)k * 8 + lane] = part[lane];
}

// ---------------- LayerNorm over 256, fp32 in -> bf16 out ----------------
__global__ __launch_bounds__(256) void ln256_kernel(
    const float* __restrict__ x, const float* __restrict__ g,
    const float* __restrict__ b, __bf16* __restrict__ y) {
  int row = blockIdx.x, tid = threadIdx.x;
  __shared__ float red[4];
  float v = x[(size_t)row * 256 + tid];
  float s = wave_sum(v);
  int wid = tid >> 6, lane = tid & 63;
  if (lane == 0) red[wid] = s;
  __syncthreads();
  float mu = (red[0] + red[1] + red[2] + red[3]) * (1.f / 256.f);
  __syncthreads();
  float d = v - mu;
  float s2 = wave_sum(d * d);
  if (lane == 0) red[wid] = s2;
  __syncthreads();
  float var = (red[0] + red[1] + red[2] + red[3]) * (1.f / 256.f);
  float rs = rsqrtf(var + 1e-5f);
  y[(size_t)row * 256 + tid] = (__bf16)(d * rs * g[tid] + b[tid]);
}

// ---------------- bf16 MFMA GEMM: C[M,N] = A[M,K] @ BT[N,K]^T (+bias) ----------------
// MODE 0: f32 out (+ACC adds prev), MODE 1: bf16 row-major, MODE 2: bf16 scattered into vT.
template <int MODE, int ACC>
__global__ __launch_bounds__(256) void hgemm(
    const __bf16* __restrict__ A, int lda,
    const __bf16* __restrict__ BT, int Kdim,
    const float* __restrict__ bias,
    void* __restrict__ Cout, int ldc) {
  __shared__ __bf16 As[128][40];
  __shared__ __bf16 Bs[128][40];
  int tid = threadIdx.x;
  int bn = blockIdx.x * 128, bm = blockIdx.y * 128;
  int wid = tid >> 6, lane = tid & 63;
  int wr = wid >> 1, wc = wid & 1;
  int lg = lane >> 4, li = lane & 15;
  floatx4 acc[4][4];
  #pragma unroll
  for (int i = 0; i < 4; ++i)
    #pragma unroll
    for (int j = 0; j < 4; ++j) acc[i][j] = (floatx4)(0.f);

  int arow = tid >> 2, aseg = tid & 3;
  for (int k0 = 0; k0 < Kdim; k0 += 32) {
    __syncthreads();
    *(bf16x8*)&As[arow][aseg * 8] =
        *(const bf16x8*)(A + (size_t)(bm + arow) * lda + k0 + aseg * 8);
    *(bf16x8*)&As[arow + 64][aseg * 8] =
        *(const bf16x8*)(A + (size_t)(bm + arow + 64) * lda + k0 + aseg * 8);
    *(bf16x8*)&Bs[arow][aseg * 8] =
        *(const bf16x8*)(BT + (size_t)(bn + arow) * Kdim + k0 + aseg * 8);
    *(bf16x8*)&Bs[arow + 64][aseg * 8] =
        *(const bf16x8*)(BT + (size_t)(bn + arow + 64) * Kdim + k0 + aseg * 8);
    __syncthreads();
    bf16x8 af[4], bfr[4];
    #pragma unroll
    for (int mi = 0; mi < 4; ++mi)
      af[mi] = *(const bf16x8*)&As[wr * 64 + mi * 16 + li][lg * 8];
    #pragma unroll
    for (int ni = 0; ni < 4; ++ni)
      bfr[ni] = *(const bf16x8*)&Bs[wc * 64 + ni * 16 + li][lg * 8];
    #pragma unroll
    for (int mi = 0; mi < 4; ++mi)
      #pragma unroll
      for (int ni = 0; ni < 4; ++ni)
        acc[mi][ni] = __builtin_amdgcn_mfma_f32_16x16x32_bf16(af[mi], bfr[ni], acc[mi][ni], 0, 0, 0);
  }
  #pragma unroll
  for (int mi = 0; mi < 4; ++mi) {
    int row = bm + wr * 64 + mi * 16 + lg * 4;
    #pragma unroll
    for (int ni = 0; ni < 4; ++ni) {
      int col = bn + wc * 64 + ni * 16 + li;
      if (MODE == 2) {
        // scatter into vT[bh][128][1024]: bh=(row>>10)*4 + col>>7, d=col&127, t=row&1023
        __bf16 o4[4];
        #pragma unroll
        for (int r = 0; r < 4; ++r) o4[r] = (__bf16)acc[mi][ni][r];
        __bf16* vt = (__bf16*)Cout;
        size_t off = ((size_t)((row >> 10) * 4 + (col >> 7)) * 128 + (col & 127)) * 1024 + (row & 1023);
        *(uint2*)(vt + off) = *(uint2*)o4;
      } else {
        float bz = bias ? bias[col] : 0.f;
        if (MODE == 1) {
          __bf16* C = (__bf16*)Cout;
          #pragma unroll
          for (int r = 0; r < 4; ++r)
            C[(size_t)(row + r) * ldc + col] = (__bf16)(acc[mi][ni][r] + bz);
        } else {
          float* C = (float*)Cout;
          #pragma unroll
          for (int r = 0; r < 4; ++r) {
            float v = acc[mi][ni][r] + bz;
            if (ACC) v += C[(size_t)(row + r) * ldc + col];
            C[(size_t)(row + r) * ldc + col] = v;
          }
        }
      }
    }
  }
}

// ---------------- causal depthwise conv (K=4) + SiLU, vectorized 8 ch/thread ----------------
__global__ __launch_bounds__(256) void conv_silu_kernel(
    const __bf16* __restrict__ up, const float* __restrict__ cw,
    const float* __restrict__ cb, __bf16* __restrict__ xc) {
  int idx = blockIdx.x * 256 + threadIdx.x;  // 8192*64
  int row = idx >> 6;
  int c8 = (idx & 63) * 8;
  int t = row & (S - 1);
  float acc[8];
  *(float4*)&acc[0] = *(const float4*)(cb + c8);
  *(float4*)&acc[4] = *(const float4*)(cb + c8 + 4);
  #pragma unroll
  for (int j = 0; j < 4; ++j) {
    int tt = t - 3 + j;
    if (tt >= 0) {
      bf16x8 xv = *(const bf16x8*)(up + (size_t)(row - 3 + j) * 1024 + c8);
      float4 w0 = *(const float4*)(cw + j * 512 + c8);
      float4 w1 = *(const float4*)(cw + j * 512 + c8 + 4);
      acc[0] += w0.x * (float)xv[0]; acc[1] += w0.y * (float)xv[1];
      acc[2] += w0.z * (float)xv[2]; acc[3] += w0.w * (float)xv[3];
      acc[4] += w1.x * (float)xv[4]; acc[5] += w1.y * (float)xv[5];
      acc[6] += w1.z * (float)xv[6]; acc[7] += w1.w * (float)xv[7];
    }
  }
  bf16x8 o;
  #pragma unroll
  for (int m = 0; m < 8; ++m) {
    float sg = 1.f / (1.f + __expf(-acc[m]));
    o[m] = (__bf16)(acc[m] * sg);
  }
  *(bf16x8*)(xc + (size_t)row * 512 + c8) = o;
}

// ---------------- gates = xc@Wg1 + xm@Wg2 + bif  (wave per row) ----------------
__global__ __launch_bounds__(256) void gates_kernel(
    const __bf16* __restrict__ xc, const __bf16* __restrict__ up,
    const float* __restrict__ wg, const float* __restrict__ bif,
    float* __restrict__ gates) {
  int tid = threadIdx.x;
  int wv = tid >> 6, lane = tid & 63;
  int row = blockIdx.x * 4 + wv;
  bf16x8 xcv = *(const bf16x8*)(xc + (size_t)row * 512 + lane * 8);
  bf16x8 xmv = *(const bf16x8*)(up + (size_t)row * 1024 + lane * 8);
  const float* w1 = wg + (size_t)(lane * 8) * 8;         // Wg1[k][8]
  const float* w2 = wg + 4096 + (size_t)(lane * 8) * 8;  // Wg2[k][8]
  float part[8] = {0, 0, 0, 0, 0, 0, 0, 0};
  #pragma unroll
  for (int m = 0; m < 8; ++m) {
    float xcf = (float)xcv[m], xmf = (float)xmv[m];
    const float* a = w1 + m * 8;
    const float* b = w2 + m * 8;
    #pragma unroll
    for (int j = 0; j < 8; ++j) part[j] += xcf * a[j] + xmf * b[j];
  }
  #pragma unroll
  for (int j = 0; j < 8; ++j) part[j] = wave_sum(part[j]);
  if (lane < 8) gates[(size_t)row * 8 + lane] = part[lane] + bif[lane];
}

// ---------------- per-(b,h) gate scan: one wave, lane-serial 16 + shuffle scan ----------------
__global__ __launch_bounds__(64) void scan_kernel(
    const float* __restrict__ gates, float* __restrict__ gout,
    float* __restrict__ Mout, float* __restrict__ NFout) {
  int bh = blockIdx.x;
  int bb = bh >> 2, hh = bh & 3;
  int lane = threadIdx.x;
  float ip[16], pf[16];
  #pragma unroll
  for (int i = 0; i < 16; ++i) {
    int t = lane * 16 + i;
    const float* grow = gates + ((size_t)(bb * S + t)) * 8;
    ip[i] = grow[hh];
    float fp = grow[4 + hh];
    float lf = fminf(fp, 0.f) - log1pf(__expf(-fabsf(fp)));
    pf[i] = (i == 0) ? lf : pf[i - 1] + lf;
  }
  float T = pf[15];
  float inc = T;
  #pragma unroll
  for (int off = 1; off < 64; off <<= 1) {
    float v = __shfl_up(inc, off, 64);
    if (lane >= off) inc += v;
  }
  float excl = inc - T;
  float F[16], g[16], pm[16];
  #pragma unroll
  for (int i = 0; i < 16; ++i) {
    F[i] = excl + pf[i];
    g[i] = ip[i] - F[i];
    pm[i] = (i == 0) ? g[0] : fmaxf(pm[i - 1], g[i]);
  }
  float Mx = pm[15];
  float incm = Mx;
  #pragma unroll
  for (int off = 1; off < 64; off <<= 1) {
    float v = __shfl_up(incm, off, 64);
    if (lane >= off) incm = fmaxf(incm, v);
  }
  float em = __shfl_up(incm, 1, 64);
  if (lane == 0) em = -3.4e38f;
  #pragma unroll
  for (int i = 0; i < 16; ++i) {
    int t = lane * 16 + i;
    size_t o = (size_t)bh * S + t;
    float M = fmaxf(em, pm[i]);
    gout[o] = g[i];
    Mout[o] = M;
    NFout[o] = __expf(-F[i] - M);
  }
}

// ---------------- MFMA mLSTM attention, paired q-tiles + LDS staging ----------------
// qk: [B*S][1024] bf16, q cols 0-511, k cols 512-1023. vT: [bh][128][1024].
__global__ __launch_bounds__(256, 1) void attn_kernel(
    const __bf16* __restrict__ qk, const __bf16* __restrict__ vT,
    const float* __restrict__ gbuf, const float* __restrict__ Mbuf,
    const float* __restrict__ NFbuf, float* __restrict__ hatt) {
  __shared__ __bf16 Ks[64][136];
  __shared__ __bf16 Vs[128][72];
  __shared__ __bf16 plds[4][2][16][72];
  __shared__ float gls[64];
  int px = blockIdx.x, bh = blockIdx.y;
  int tqA = px, tqB = 15 - px;
  int bb = bh >> 2, hh = bh & 3;
  int tid = threadIdx.x;
  int wv = tid >> 6, lane = tid & 63;
  int lg = lane >> 4, li = lane & 15;
  int tbA = tqA * 64 + wv * 16;
  int tbB = tqB * 64 + wv * 16;
  const float scale = 0.08838834764831845f;

  bf16x8 aqA[4], aqB[4];
  {
    const __bf16* qpA = qk + ((size_t)(bb * S + tbA + li)) * 1024 + hh * 128 + lg * 8;
    const __bf16* qpB = qk + ((size_t)(bb * S + tbB + li)) * 1024 + hh * 128 + lg * 8;
    #pragma unroll
    for (int cd = 0; cd < 4; ++cd) {
      aqA[cd] = *(const bf16x8*)(qpA + cd * 32);
      aqB[cd] = *(const bf16x8*)(qpB + cd * 32);
    }
  }
  float mlA[4], nfA[4], mlB[4], nfB[4];
  #pragma unroll
  for (int r = 0; r < 4; ++r) {
    mlA[r] = Mbuf[(size_t)bh * S + tbA + lg * 4 + r];
    nfA[r] = NFbuf[(size_t)bh * S + tbA + lg * 4 + r];
    mlB[r] = Mbuf[(size_t)bh * S + tbB + lg * 4 + r];
    nfB[r] = NFbuf[(size_t)bh * S + tbB + lg * 4 + r];
  }

  floatx4 oA[8], oB[8];
  #pragma unroll
  for (int df = 0; df < 8; ++df) { oA[df] = (floatx4)(0.f); oB[df] = (floatx4)(0.f); }
  float rsA[4] = {0, 0, 0, 0}, rsB[4] = {0, 0, 0, 0};

  int krow = tid >> 3, kcol = tid & 7;
  bf16x8 kreg[4], vreg[4];
  float greg = 0.f;
  auto preload = [&](int st) {
    int s0 = st * 64;
    const __bf16* kp = qk + ((size_t)(bb * S + s0 + krow)) * 1024 + 512 + hh * 128;
    kreg[0] = *(const bf16x8*)(kp + kcol * 8);
    kreg[1] = *(const bf16x8*)(kp + (size_t)32 * 1024 + kcol * 8);
    kreg[2] = *(const bf16x8*)(kp + 64 + kcol * 8);
    kreg[3] = *(const bf16x8*)(kp + (size_t)32 * 1024 + 64 + kcol * 8);
    #pragma unroll
    for (int i = 0; i < 4; ++i)
      vreg[i] = *(const bf16x8*)(vT + ((size_t)(bh * 128 + krow + i * 32)) * 1024 + s0 + kcol * 8);
    if (tid < 64) greg = gbuf[(size_t)bh * S + s0 + tid];
  };
  preload(0);

  for (int st = 0; st <= tqB; ++st) {
    __syncthreads();
    *(bf16x8*)&Ks[krow][kcol * 8] = kreg[0];
    *(bf16x8*)&Ks[krow + 32][kcol * 8] = kreg[1];
    *(bf16x8*)&Ks[krow][64 + kcol * 8] = kreg[2];
    *(bf16x8*)&Ks[krow + 32][64 + kcol * 8] = kreg[3];
    #pragma unroll
    for (int i = 0; i < 4; ++i) *(bf16x8*)&Vs[krow + i * 32][kcol * 8] = vreg[i];
    if (tid < 64) gls[tid] = greg;
    __syncthreads();
    if (st < tqB) preload(st + 1);

    int s0 = st * 64;
    bool actA = (st <= tqA);
    #pragma unroll
    for (int ns = 0; ns < 4; ++ns) {
      bf16x8 bk0 = *(const bf16x8*)&Ks[ns * 16 + li][lg * 8];
      bf16x8 bk1 = *(const bf16x8*)&Ks[ns * 16 + li][32 + lg * 8];
      bf16x8 bk2 = *(const bf16x8*)&Ks[ns * 16 + li][64 + lg * 8];
      bf16x8 bk3 = *(const bf16x8*)&Ks[ns * 16 + li][96 + lg * 8];
      int s = s0 + ns * 16 + li;
      float gv = gls[ns * 16 + li];
      if (actA) {
        floatx4 pa = (floatx4)(0.f);
        pa = __builtin_amdgcn_mfma_f32_16x16x32_bf16(aqA[0], bk0, pa, 0, 0, 0);
        pa = __builtin_amdgcn_mfma_f32_16x16x32_bf16(aqA[1], bk1, pa, 0, 0, 0);
        pa = __builtin_amdgcn_mfma_f32_16x16x32_bf16(aqA[2], bk2, pa, 0, 0, 0);
        pa = __builtin_amdgcn_mfma_f32_16x16x32_bf16(aqA[3], bk3, pa, 0, 0, 0);
        #pragma unroll
        for (int r = 0; r < 4; ++r) {
          int t = tbA + lg * 4 + r;
          float val = pa[r] * scale * __expf(gv - mlA[r]);
          float w = (s <= t) ? val : 0.f;
          rsA[r] += w;
          plds[wv][0][lg * 4 + r][ns * 16 + li] = (__bf16)w;
        }
      }
      {
        floatx4 pb = (floatx4)(0.f);
        pb = __builtin_amdgcn_mfma_f32_16x16x32_bf16(aqB[0], bk0, pb, 0, 0, 0);
        pb = __builtin_amdgcn_mfma_f32_16x16x32_bf16(aqB[1], bk1, pb, 0, 0, 0);
        pb = __builtin_amdgcn_mfma_f32_16x16x32_bf16(aqB[2], bk2, pb, 0, 0, 0);
        pb = __builtin_amdgcn_mfma_f32_16x16x32_bf16(aqB[3], bk3, pb, 0, 0, 0);
        #pragma unroll
        for (int r = 0; r < 4; ++r) {
          int t = tbB + lg * 4 + r;
          float val = pb[r] * scale * __expf(gv - mlB[r]);
          float w = (s <= t) ? val : 0.f;
          rsB[r] += w;
          plds[wv][1][lg * 4 + r][ns * 16 + li] = (__bf16)w;
        }
      }
    }
    bf16x8 apA0, apA1, apB0, apB1;
    if (actA) {
      apA0 = *(const bf16x8*)&plds[wv][0][li][lg * 8];
      apA1 = *(const bf16x8*)&plds[wv][0][li][32 + lg * 8];
    }
    apB0 = *(const bf16x8*)&plds[wv][1][li][lg * 8];
    apB1 = *(const bf16x8*)&plds[wv][1][li][32 + lg * 8];
    #pragma unroll
    for (int df = 0; df < 8; ++df) {
      bf16x8 bv0 = *(const bf16x8*)&Vs[df * 16 + li][lg * 8];
      bf16x8 bv1 = *(const bf16x8*)&Vs[df * 16 + li][32 + lg * 8];
      if (actA) {
        oA[df] = __builtin_amdgcn_mfma_f32_16x16x32_bf16(apA0, bv0, oA[df], 0, 0, 0);
        oA[df] = __builtin_amdgcn_mfma_f32_16x16x32_bf16(apA1, bv1, oA[df], 0, 0, 0);
      }
      oB[df] = __builtin_amdgcn_mfma_f32_16x16x32_bf16(apB0, bv0, oB[df], 0, 0, 0);
      oB[df] = __builtin_amdgcn_mfma_f32_16x16x32_bf16(apB1, bv1, oB[df], 0, 0, 0);
    }
  }
  #pragma unroll
  for (int r = 0; r < 4; ++r) {
    float a = rsA[r], b = rsB[r];
    a += __shfl_xor(a, 1, 64); a += __shfl_xor(a, 2, 64);
    a += __shfl_xor(a, 4, 64); a += __shfl_xor(a, 8, 64);
    b += __shfl_xor(b, 1, 64); b += __shfl_xor(b, 2, 64);
    b += __shfl_xor(b, 4, 64); b += __shfl_xor(b, 8, 64);
    rsA[r] = a; rsB[r] = b;
  }
  #pragma unroll
  for (int r = 0; r < 4; ++r) {
    float invA = 1.f / (fmaxf(fabsf(rsA[r]), nfA[r]) + 1e-6f);
    float invB = 1.f / (fmaxf(fabsf(rsB[r]), nfB[r]) + 1e-6f);
    float* obA = hatt + ((size_t)(bb * S + tbA + lg * 4 + r)) * 512 + hh * 128 + li;
    float* obB = hatt + ((size_t)(bb * S + tbB + lg * 4 + r)) * 512 + hh * 128 + li;
    #pragma unroll
    for (int df = 0; df < 8; ++df) {
      obA[df * 16] = oA[df][r] * invA;
      obB[df * 16] = oB[df][r] * invB;
    }
  }
}

// ---------------- GroupNorm + skip*xc + *silu(z): hatt f32 -> hd bf16 ----------------
__global__ __launch_bounds__(512) void gn_kernel(
    const float* __restrict__ hatt, const float* __restrict__ gg,
    const float* __restrict__ gb, const float* __restrict__ skip,
    const __bf16* __restrict__ xc, const __bf16* __restrict__ up,
    __bf16* __restrict__ hd) {
  int row = blockIdx.x, tid = threadIdx.x;
  int head = tid >> 7;
  __shared__ float red[8];
  float v = hatt[(size_t)row * 512 + tid];
  float s = wave_sum(v);
  int wid = tid >> 6, lane = tid & 63;
  if (lane == 0) red[wid] = s;
  __syncthreads();
  float mu = (red[head * 2] + red[head * 2 + 1]) * (1.f / 128.f);
  __syncthreads();
  float d = v - mu;
  float s2 = wave_sum(d * d);
  if (lane == 0) red[wid] = s2;
  __syncthreads();
  float var = (red[head * 2] + red[head * 2 + 1]) * (1.f / 128.f);
  float rsq = rsqrtf(var + 1e-5f);
  float ln = d * rsq * gg[tid] + gb[tid];
  float val = ln + skip[tid] * (float)xc[(size_t)row * 512 + tid];
  float z = (float)up[(size_t)row * 1024 + 512 + tid];
  float sg = 1.f / (1.f + expf(-z));
  hd[(size_t)row * 512 + tid] = (__bf16)(val * (z * sg));
}

// ---------------- final LN + head ----------------
__global__ __launch_bounds__(256) void final_kernel(
    const float* __restrict__ h, const float* __restrict__ g,
    const float* __restrict__ b, const float* __restrict__ Wf,
    const float* __restrict__ bf, float* __restrict__ out) {
  int bb = blockIdx.x, tid = threadIdx.x;
  size_t row = (size_t)(bb * S + S - 1) * 256;
  __shared__ float red[4];
  float v = h[row + tid];
  float s = wave_sum(v);
  int wid = tid >> 6, lane = tid & 63;
  if (lane == 0) red[wid] = s;
  __syncthreads();
  float mu = (red[0] + red[1] + red[2] + red[3]) * (1.f / 256.f);
  __syncthreads();
  float d = v - mu;
  float s2 = wave_sum(d * d);
  if (lane == 0) red[wid] = s2;
  __syncthreads();
  float var = (red[0] + red[1] + red[2] + red[3]) * (1.f / 256.f);
  float rs = rsqrtf(var + 1e-5f);
  float ln = d * rs * g[tid] + b[tid];
  float p = ln * Wf[tid];
  float psum = wave_sum(p);
  __syncthreads();
  if (lane == 0) red[wid] = psum;
  __syncthreads();
  if (tid == 0) out[bb] = red[0] + red[1] + red[2] + red[3] + bf[0];
}

extern "C" void kernel_launch(void* const* d_in, const int* in_sizes, int n_in,
                              void* d_out, int out_size, void* d_ws, size_t ws_size,
                              hipStream_t stream) {
  const float* x      = (const float*)d_in[0];
  const float* tf     = (const float*)d_in[1];
  const float* Wp     = (const float*)d_in[2];
  const float* bp     = (const float*)d_in[3];
  const float* ln_g   = (const float*)d_in[4];
  const float* ln_b   = (const float*)d_in[5];
  const float* Wup    = (const float*)d_in[6];
  const float* bup    = (const float*)d_in[7];
  const float* conv_w = (const float*)d_in[8];
  const float* conv_b = (const float*)d_in[9];
  const float* Wq     = (const float*)d_in[10];
  const float* Wk     = (const float*)d_in[11];
  const float* Wv     = (const float*)d_in[12];
  const float* Wif    = (const float*)d_in[13];
  const float* bif    = (const float*)d_in[14];
  const float* gn_g   = (const float*)d_in[15];
  const float* gn_b   = (const float*)d_in[16];
  const float* skip   = (const float*)d_in[17];
  const float* Wdown  = (const float*)d_in[18];
  const float* bdown  = (const float*)d_in[19];
  const float* lnf_g  = (const float*)d_in[20];
  const float* lnf_b  = (const float*)d_in[21];
  const float* Wf     = (const float*)d_in[22];
  const float* bf     = (const float*)d_in[23];
  float* out = (float*)d_out;

  float* h     = (float*)d_ws;              // 2,097,152 f32
  float* hatt  = h + 2097152;               // 4,194,304 f32
  float* gates = hatt + 4194304;            // 65,536 f32
  float* gbuf  = gates + 65536;             // 32,768
  float* Mbuf  = gbuf + 32768;              // 32,768
  float* NFbuf = Mbuf + 32768;              // 32,768
  float* wgbuf = NFbuf + 32768;             // 32,768 (4 layers x 2 x 512 x 8)
  __bf16* hn   = (__bf16*)(wgbuf + 32768);  // 2,097,152 bf16
  __bf16* up   = hn + 2097152;              // 8,388,608
  __bf16* xc   = up + 8388608;              // 4,194,304
  __bf16* qk   = xc + 4194304;              // 8,388,608
  __bf16* vT   = qk + 8388608;              // 4,194,304
  __bf16* hd   = vT + 4194304;              // 4,194,304
  __bf16* WupT   = hd + 4194304;            // 1,048,576
  __bf16* WqkT   = WupT + 1048576;          // 2,097,152
  __bf16* WvT    = WqkT + 2097152;          // 1,048,576
  __bf16* WdownT = WvT + 1048576;           // 524,288
  // ~98 MB total

  wtrans_kernel<<<4608, 256, 0, stream>>>(Wup, Wq, Wk, Wv, Wdown,
                                          WupT, WqkT, WvT, WdownT);
  wgprep_kernel<<<1024, 256, 0, stream>>>(Wq, Wk, Wv, Wif, wgbuf);
  embed_kernel<<<8192, 256, 0, stream>>>(x, tf, Wp, bp, h);
  for (int l = 0; l < NLAYER; ++l) {
    ln256_kernel<<<8192, 256, 0, stream>>>(h, ln_g + l * 256, ln_b + l * 256, hn);
    hgemm<1, 0><<<dim3(8, 64), 256, 0, stream>>>(
        hn, 256, WupT + (size_t)l * 262144, 256, bup + l * 1024, up, 1024);
    conv_silu_kernel<<<2048, 256, 0, stream>>>(up, conv_w + l * 2048, conv_b + l * 512, xc);
    hgemm<1, 0><<<dim3(8, 64), 256, 0, stream>>>(
        xc, 512, WqkT + (size_t)l * 524288, 512, nullptr, qk, 1024);
    hgemm<2, 0><<<dim3(4, 64), 256, 0, stream>>>(
        up, 1024, WvT + (size_t)l * 262144, 512, nullptr, vT, 0);
    gates_kernel<<<2048, 256, 0, stream>>>(xc, up, wgbuf + l * 8192, bif + l * 8, gates);
    scan_kernel<<<32, 64, 0, stream>>>(gates, gbuf, Mbuf, NFbuf);
    attn_kernel<<<dim3(8, 32), 256, 0, stream>>>(qk, vT, gbuf, Mbuf, NFbuf, hatt);
    gn_kernel<<<8192, 512, 0, stream>>>(hatt, gn_g + l * 512, gn_b + l * 512,
                                        skip + l * 512, xc, up, hd);
    hgemm<0, 1><<<dim3(2, 64), 256, 0, stream>>>(
        hd, 512, WdownT + (size_t)l * 131072, 512, bdown + l * 256, h, 256);
  }
  final_kernel<<<8, 256, 0, stream>>>(h, lnf_g, lnf_b, Wf, bf, out);
}

// Round 7
// 744.875 us; speedup vs baseline: 1.3124x; 1.1467x over previous
//
#include <hip/hip_runtime.h>
#include <hip/hip_bf16.h>
#include <math.h>

#define S 1024
#define NLAYER 4

typedef __bf16 bf16x8 __attribute__((ext_vector_type(8)));
typedef float floatx4 __attribute__((ext_vector_type(4)));

__device__ __forceinline__ float wave_sum(float v) {
  #pragma unroll
  for (int off = 32; off > 0; off >>= 1) v += __shfl_xor(v, off, 64);
  return v;
}

// ---------------- embed: h = [x, tf] @ Wp + bp (fp32) + fused LN(layer0) ----------------
__global__ __launch_bounds__(256) void embed_kernel(
    const float* __restrict__ x, const float* __restrict__ tf,
    const float* __restrict__ Wp, const float* __restrict__ bp,
    const float* __restrict__ g, const float* __restrict__ b,
    float* __restrict__ h, __bf16* __restrict__ hn) {
  int row = blockIdx.x;
  int n = threadIdx.x;
  float xv = x[row];
  const float* t4 = tf + (size_t)row * 4;
  float acc = bp[n] + xv * Wp[n];
  acc += t4[0] * Wp[256 + n];
  acc += t4[1] * Wp[512 + n];
  acc += t4[2] * Wp[768 + n];
  acc += t4[3] * Wp[1024 + n];
  h[(size_t)row * 256 + n] = acc;
  // fused LN over the 256 columns
  __shared__ float red[4];
  int wid = n >> 6, lane = n & 63;
  float s = wave_sum(acc);
  if (lane == 0) red[wid] = s;
  __syncthreads();
  float mu = (red[0] + red[1] + red[2] + red[3]) * (1.f / 256.f);
  __syncthreads();
  float d = acc - mu;
  float s2 = wave_sum(d * d);
  if (lane == 0) red[wid] = s2;
  __syncthreads();
  float var = (red[0] + red[1] + red[2] + red[3]) * (1.f / 256.f);
  float rs = rsqrtf(var + 1e-5f);
  hn[(size_t)row * 256 + n] = (__bf16)(d * rs * g[n] + b[n]);
}

// ---------------- weight transpose+cast: W[K][N] f32 -> WT[N][K] bf16 ----------------
__global__ __launch_bounds__(256) void wtrans_kernel(
    const float* __restrict__ Wup, const float* __restrict__ Wq,
    const float* __restrict__ Wk, const float* __restrict__ Wv,
    const float* __restrict__ Wdown,
    __bf16* __restrict__ WupT, __bf16* __restrict__ WqkT,
    __bf16* __restrict__ WvT, __bf16* __restrict__ WdownT) {
  __shared__ float T[32][33];
  int bid = blockIdx.x;
  int layer = bid / 1152, rr = bid % 1152;
  const float* src; __bf16* dst; int K, N, tile;
  if (rr < 256)       { src = Wup   + layer * 262144; dst = WupT  + layer * 262144;          K = 256; N = 1024; tile = rr; }
  else if (rr < 512)  { src = Wq    + layer * 262144; dst = WqkT  + layer * 524288;          K = 512; N = 512;  tile = rr - 256; }
  else if (rr < 768)  { src = Wk    + layer * 262144; dst = WqkT  + layer * 524288 + 262144; K = 512; N = 512;  tile = rr - 512; }
  else if (rr < 1024) { src = Wv    + layer * 262144; dst = WvT   + layer * 262144;          K = 512; N = 512;  tile = rr - 768; }
  else                { src = Wdown + layer * 131072; dst = WdownT + layer * 131072;         K = 512; N = 256;  tile = rr - 1024; }
  int ntn = N >> 5;
  int tk = tile / ntn, tn = tile % ntn;
  int tid = threadIdx.x;
  int r = tid >> 3, c4 = (tid & 7) * 4;
  float4 v = *(const float4*)(src + (size_t)(tk * 32 + r) * N + tn * 32 + c4);
  T[c4 + 0][r] = v.x; T[c4 + 1][r] = v.y; T[c4 + 2][r] = v.z; T[c4 + 3][r] = v.w;
  __syncthreads();
  __bf16 o[4];
  #pragma unroll
  for (int j = 0; j < 4; ++j) o[j] = (__bf16)T[r][c4 + j];
  *(uint2*)(dst + (size_t)(tn * 32 + r) * K + tk * 32 + c4) = *(uint2*)o;
}

// ---------------- Wg precompute (coalesced wave-per-row) ----------------
__global__ __launch_bounds__(256) void wgprep_kernel(
    const float* __restrict__ Wq, const float* __restrict__ Wk,
    const float* __restrict__ Wv, const float* __restrict__ Wif,
    float* __restrict__ wg) {
  int bid = blockIdx.x;      // 1024 blocks: 256 per layer
  int l = bid >> 8;
  int rem = bid & 255;
  int sel = rem >> 7;
  int kg = rem & 127;
  int tid = threadIdx.x;
  int wv = tid >> 6, lane = tid & 63;
  int k = kg * 4 + wv;
  const float* wif = Wif + (size_t)l * 1536 * 8;
  float part[8] = {0, 0, 0, 0, 0, 0, 0, 0};
  if (sel == 0) {
    const float* qr = Wq + (size_t)l * 262144 + (size_t)k * 512;
    const float* kr = Wk + (size_t)l * 262144 + (size_t)k * 512;
    #pragma unroll
    for (int i = 0; i < 8; ++i) {
      int n = lane + i * 64;
      float qv = qr[n], kv = kr[n];
      const float* wq8 = wif + (size_t)n * 8;
      const float* wk8 = wif + (size_t)(512 + n) * 8;
      #pragma unroll
      for (int j = 0; j < 8; ++j) part[j] += qv * wq8[j] + kv * wk8[j];
    }
  } else {
    const float* vr = Wv + (size_t)l * 262144 + (size_t)k * 512;
    #pragma unroll
    for (int i = 0; i < 8; ++i) {
      int n = lane + i * 64;
      float vv = vr[n];
      const float* wv8 = wif + (size_t)(1024 + n) * 8;
      #pragma unroll
      for (int j = 0; j < 8; ++j) part[j] += vv * wv8[j];
    }
  }
  #pragma unroll
  for (int j = 0; j < 8; ++j) part[j] = wave_sum(part[j]);
  if (lane < 8) wg[(size_t)l * 8192 + sel * 4096 + (size_t)k * 8 + lane] = part[lane];
}

// ---------------- LayerNorm over 256, fp32 in -> bf16 out ----------------
__global__ __launch_bounds__(256) void ln256_kernel(
    const float* __restrict__ x, const float* __restrict__ g,
    const float* __restrict__ b, __bf16* __restrict__ y) {
  int row = blockIdx.x, tid = threadIdx.x;
  __shared__ float red[4];
  float v = x[(size_t)row * 256 + tid];
  float s = wave_sum(v);
  int wid = tid >> 6, lane = tid & 63;
  if (lane == 0) red[wid] = s;
  __syncthreads();
  float mu = (red[0] + red[1] + red[2] + red[3]) * (1.f / 256.f);
  __syncthreads();
  float d = v - mu;
  float s2 = wave_sum(d * d);
  if (lane == 0) red[wid] = s2;
  __syncthreads();
  float var = (red[0] + red[1] + red[2] + red[3]) * (1.f / 256.f);
  float rs = rsqrtf(var + 1e-5f);
  y[(size_t)row * 256 + tid] = (__bf16)(d * rs * g[tid] + b[tid]);
}

// ---------------- bf16 MFMA GEMM with register prefetch ----------------
// MODE 0: f32 out (+ACC adds prev), MODE 1: bf16 row-major, MODE 2: bf16 scattered into vT.
template <int MODE, int ACC>
__global__ __launch_bounds__(256) void hgemm(
    const __bf16* __restrict__ A, int lda,
    const __bf16* __restrict__ BT, int Kdim,
    const float* __restrict__ bias,
    void* __restrict__ Cout, int ldc) {
  __shared__ __bf16 As[128][40];
  __shared__ __bf16 Bs[128][40];
  int tid = threadIdx.x;
  int bn = blockIdx.x * 128, bm = blockIdx.y * 128;
  int wid = tid >> 6, lane = tid & 63;
  int wr = wid >> 1, wc = wid & 1;
  int lg = lane >> 4, li = lane & 15;
  floatx4 acc[4][4];
  #pragma unroll
  for (int i = 0; i < 4; ++i)
    #pragma unroll
    for (int j = 0; j < 4; ++j) acc[i][j] = (floatx4)(0.f);

  int arow = tid >> 2, aseg = tid & 3;
  bf16x8 pa0, pa1, pb0, pb1;
  auto pre = [&](int k0) {
    pa0 = *(const bf16x8*)(A + (size_t)(bm + arow) * lda + k0 + aseg * 8);
    pa1 = *(const bf16x8*)(A + (size_t)(bm + arow + 64) * lda + k0 + aseg * 8);
    pb0 = *(const bf16x8*)(BT + (size_t)(bn + arow) * Kdim + k0 + aseg * 8);
    pb1 = *(const bf16x8*)(BT + (size_t)(bn + arow + 64) * Kdim + k0 + aseg * 8);
  };
  pre(0);
  for (int k0 = 0; k0 < Kdim; k0 += 32) {
    __syncthreads();
    *(bf16x8*)&As[arow][aseg * 8] = pa0;
    *(bf16x8*)&As[arow + 64][aseg * 8] = pa1;
    *(bf16x8*)&Bs[arow][aseg * 8] = pb0;
    *(bf16x8*)&Bs[arow + 64][aseg * 8] = pb1;
    __syncthreads();
    if (k0 + 32 < Kdim) pre(k0 + 32);
    bf16x8 af[4], bfr[4];
    #pragma unroll
    for (int mi = 0; mi < 4; ++mi)
      af[mi] = *(const bf16x8*)&As[wr * 64 + mi * 16 + li][lg * 8];
    #pragma unroll
    for (int ni = 0; ni < 4; ++ni)
      bfr[ni] = *(const bf16x8*)&Bs[wc * 64 + ni * 16 + li][lg * 8];
    #pragma unroll
    for (int mi = 0; mi < 4; ++mi)
      #pragma unroll
      for (int ni = 0; ni < 4; ++ni)
        acc[mi][ni] = __builtin_amdgcn_mfma_f32_16x16x32_bf16(af[mi], bfr[ni], acc[mi][ni], 0, 0, 0);
  }
  #pragma unroll
  for (int mi = 0; mi < 4; ++mi) {
    int row = bm + wr * 64 + mi * 16 + lg * 4;
    #pragma unroll
    for (int ni = 0; ni < 4; ++ni) {
      int col = bn + wc * 64 + ni * 16 + li;
      if (MODE == 2) {
        __bf16 o4[4];
        #pragma unroll
        for (int r = 0; r < 4; ++r) o4[r] = (__bf16)acc[mi][ni][r];
        __bf16* vt = (__bf16*)Cout;
        size_t off = ((size_t)((row >> 10) * 4 + (col >> 7)) * 128 + (col & 127)) * 1024 + (row & 1023);
        *(uint2*)(vt + off) = *(uint2*)o4;
      } else {
        float bz = bias ? bias[col] : 0.f;
        if (MODE == 1) {
          __bf16* C = (__bf16*)Cout;
          #pragma unroll
          for (int r = 0; r < 4; ++r)
            C[(size_t)(row + r) * ldc + col] = (__bf16)(acc[mi][ni][r] + bz);
        } else {
          float* C = (float*)Cout;
          #pragma unroll
          for (int r = 0; r < 4; ++r) {
            float v = acc[mi][ni][r] + bz;
            if (ACC) v += C[(size_t)(row + r) * ldc + col];
            C[(size_t)(row + r) * ldc + col] = v;
          }
        }
      }
    }
  }
}

// ---------------- causal conv (K=4) + SiLU + fused gate projection ----------------
// wave per row: lane handles channels [lane*8, lane*8+8). Writes xc and gates.
__global__ __launch_bounds__(256) void conv_silu_kernel(
    const __bf16* __restrict__ up, const float* __restrict__ cw,
    const float* __restrict__ cb, const float* __restrict__ wg,
    const float* __restrict__ bif, __bf16* __restrict__ xc,
    float* __restrict__ gates) {
  int tid = threadIdx.x;
  int wv = tid >> 6, lane = tid & 63;
  int row = blockIdx.x * 4 + wv;
  int c8 = lane * 8;
  int t = row & (S - 1);
  float acc[8];
  *(float4*)&acc[0] = *(const float4*)(cb + c8);
  *(float4*)&acc[4] = *(const float4*)(cb + c8 + 4);
  float xm[8];
  #pragma unroll
  for (int j = 0; j < 4; ++j) {
    int tt = t - 3 + j;
    if (tt >= 0) {
      bf16x8 xv = *(const bf16x8*)(up + (size_t)(row - 3 + j) * 1024 + c8);
      float4 w0 = *(const float4*)(cw + j * 512 + c8);
      float4 w1 = *(const float4*)(cw + j * 512 + c8 + 4);
      acc[0] += w0.x * (float)xv[0]; acc[1] += w0.y * (float)xv[1];
      acc[2] += w0.z * (float)xv[2]; acc[3] += w0.w * (float)xv[3];
      acc[4] += w1.x * (float)xv[4]; acc[5] += w1.y * (float)xv[5];
      acc[6] += w1.z * (float)xv[6]; acc[7] += w1.w * (float)xv[7];
      if (j == 3) {
        #pragma unroll
        for (int m = 0; m < 8; ++m) xm[m] = (float)xv[m];
      }
    }
  }
  bf16x8 o;
  float xcs[8];
  #pragma unroll
  for (int m = 0; m < 8; ++m) {
    float sg = 1.f / (1.f + __expf(-acc[m]));
    xcs[m] = acc[m] * sg;
    o[m] = (__bf16)xcs[m];
  }
  *(bf16x8*)(xc + (size_t)row * 512 + c8) = o;
  // fused gates: part[j] = sum_c xc[c]*Wg1[c][j] + xm[c]*Wg2[c][j]
  const float* w1 = wg + (size_t)c8 * 8;
  const float* w2 = wg + 4096 + (size_t)c8 * 8;
  float part[8] = {0, 0, 0, 0, 0, 0, 0, 0};
  #pragma unroll
  for (int m = 0; m < 8; ++m) {
    const float* a = w1 + m * 8;
    const float* b = w2 + m * 8;
    #pragma unroll
    for (int j = 0; j < 8; ++j) part[j] += xcs[m] * a[j] + xm[m] * b[j];
  }
  #pragma unroll
  for (int j = 0; j < 8; ++j) part[j] = wave_sum(part[j]);
  if (lane < 8) gates[(size_t)row * 8 + lane] = part[lane] + bif[lane];
}

// ---------------- per-(b,h) gate scan: one wave ----------------
__global__ __launch_bounds__(64) void scan_kernel(
    const float* __restrict__ gates, float* __restrict__ gout,
    float* __restrict__ Mout, float* __restrict__ NFout) {
  int bh = blockIdx.x;
  int bb = bh >> 2, hh = bh & 3;
  int lane = threadIdx.x;
  float ip[16], pf[16];
  #pragma unroll
  for (int i = 0; i < 16; ++i) {
    int t = lane * 16 + i;
    const float* grow = gates + ((size_t)(bb * S + t)) * 8;
    ip[i] = grow[hh];
    float fp = grow[4 + hh];
    float lf = fminf(fp, 0.f) - log1pf(__expf(-fabsf(fp)));
    pf[i] = (i == 0) ? lf : pf[i - 1] + lf;
  }
  float T = pf[15];
  float inc = T;
  #pragma unroll
  for (int off = 1; off < 64; off <<= 1) {
    float v = __shfl_up(inc, off, 64);
    if (lane >= off) inc += v;
  }
  float excl = inc - T;
  float F[16], g[16], pm[16];
  #pragma unroll
  for (int i = 0; i < 16; ++i) {
    F[i] = excl + pf[i];
    g[i] = ip[i] - F[i];
    pm[i] = (i == 0) ? g[0] : fmaxf(pm[i - 1], g[i]);
  }
  float Mx = pm[15];
  float incm = Mx;
  #pragma unroll
  for (int off = 1; off < 64; off <<= 1) {
    float v = __shfl_up(incm, off, 64);
    if (lane >= off) incm = fmaxf(incm, v);
  }
  float em = __shfl_up(incm, 1, 64);
  if (lane == 0) em = -3.4e38f;
  #pragma unroll
  for (int i = 0; i < 16; ++i) {
    int t = lane * 16 + i;
    size_t o = (size_t)bh * S + t;
    float M = fmaxf(em, pm[i]);
    gout[o] = g[i];
    Mout[o] = M;
    NFout[o] = __expf(-F[i] - M);
  }
}

// ---------------- MFMA mLSTM attention + fused GroupNorm/skip/silu-gate ----------------
// writes hd bf16 directly (no hatt round-trip).
__global__ __launch_bounds__(256, 1) void attn_kernel(
    const __bf16* __restrict__ qk, const __bf16* __restrict__ vT,
    const float* __restrict__ gbuf, const float* __restrict__ Mbuf,
    const float* __restrict__ NFbuf,
    const float* __restrict__ gn_g, const float* __restrict__ gn_b,
    const float* __restrict__ skip,
    const __bf16* __restrict__ xc, const __bf16* __restrict__ up,
    __bf16* __restrict__ hd) {
  __shared__ __bf16 Ks[64][136];
  __shared__ __bf16 Vs[128][72];
  __shared__ __bf16 plds[4][2][16][72];
  __shared__ float gls[64];
  __shared__ float glds[128], blds[128], slds[128];
  int px = blockIdx.x, bh = blockIdx.y;
  int tqA = px, tqB = 15 - px;
  int bb = bh >> 2, hh = bh & 3;
  int tid = threadIdx.x;
  int wv = tid >> 6, lane = tid & 63;
  int lg = lane >> 4, li = lane & 15;
  int tbA = tqA * 64 + wv * 16;
  int tbB = tqB * 64 + wv * 16;
  const float scale = 0.08838834764831845f;

  if (tid < 128) {
    glds[tid] = gn_g[hh * 128 + tid];
    blds[tid] = gn_b[hh * 128 + tid];
    slds[tid] = skip[hh * 128 + tid];
  }

  bf16x8 aqA[4], aqB[4];
  {
    const __bf16* qpA = qk + ((size_t)(bb * S + tbA + li)) * 1024 + hh * 128 + lg * 8;
    const __bf16* qpB = qk + ((size_t)(bb * S + tbB + li)) * 1024 + hh * 128 + lg * 8;
    #pragma unroll
    for (int cd = 0; cd < 4; ++cd) {
      aqA[cd] = *(const bf16x8*)(qpA + cd * 32);
      aqB[cd] = *(const bf16x8*)(qpB + cd * 32);
    }
  }
  float mlA[4], nfA[4], mlB[4], nfB[4];
  #pragma unroll
  for (int r = 0; r < 4; ++r) {
    mlA[r] = Mbuf[(size_t)bh * S + tbA + lg * 4 + r];
    nfA[r] = NFbuf[(size_t)bh * S + tbA + lg * 4 + r];
    mlB[r] = Mbuf[(size_t)bh * S + tbB + lg * 4 + r];
    nfB[r] = NFbuf[(size_t)bh * S + tbB + lg * 4 + r];
  }

  floatx4 oA[8], oB[8];
  #pragma unroll
  for (int df = 0; df < 8; ++df) { oA[df] = (floatx4)(0.f); oB[df] = (floatx4)(0.f); }
  float rsA[4] = {0, 0, 0, 0}, rsB[4] = {0, 0, 0, 0};

  int krow = tid >> 3, kcol = tid & 7;
  bf16x8 kreg[4], vreg[4];
  float greg = 0.f;
  auto preload = [&](int st) {
    int s0 = st * 64;
    const __bf16* kp = qk + ((size_t)(bb * S + s0 + krow)) * 1024 + 512 + hh * 128;
    kreg[0] = *(const bf16x8*)(kp + kcol * 8);
    kreg[1] = *(const bf16x8*)(kp + (size_t)32 * 1024 + kcol * 8);
    kreg[2] = *(const bf16x8*)(kp + 64 + kcol * 8);
    kreg[3] = *(const bf16x8*)(kp + (size_t)32 * 1024 + 64 + kcol * 8);
    #pragma unroll
    for (int i = 0; i < 4; ++i)
      vreg[i] = *(const bf16x8*)(vT + ((size_t)(bh * 128 + krow + i * 32)) * 1024 + s0 + kcol * 8);
    if (tid < 64) greg = gbuf[(size_t)bh * S + s0 + tid];
  };
  preload(0);

  for (int st = 0; st <= tqB; ++st) {
    __syncthreads();
    *(bf16x8*)&Ks[krow][kcol * 8] = kreg[0];
    *(bf16x8*)&Ks[krow + 32][kcol * 8] = kreg[1];
    *(bf16x8*)&Ks[krow][64 + kcol * 8] = kreg[2];
    *(bf16x8*)&Ks[krow + 32][64 + kcol * 8] = kreg[3];
    #pragma unroll
    for (int i = 0; i < 4; ++i) *(bf16x8*)&Vs[krow + i * 32][kcol * 8] = vreg[i];
    if (tid < 64) gls[tid] = greg;
    __syncthreads();
    if (st < tqB) preload(st + 1);

    int s0 = st * 64;
    bool actA = (st <= tqA);
    #pragma unroll
    for (int ns = 0; ns < 4; ++ns) {
      bf16x8 bk0 = *(const bf16x8*)&Ks[ns * 16 + li][lg * 8];
      bf16x8 bk1 = *(const bf16x8*)&Ks[ns * 16 + li][32 + lg * 8];
      bf16x8 bk2 = *(const bf16x8*)&Ks[ns * 16 + li][64 + lg * 8];
      bf16x8 bk3 = *(const bf16x8*)&Ks[ns * 16 + li][96 + lg * 8];
      int s = s0 + ns * 16 + li;
      float gv = gls[ns * 16 + li];
      if (actA) {
        floatx4 pa = (floatx4)(0.f);
        pa = __builtin_amdgcn_mfma_f32_16x16x32_bf16(aqA[0], bk0, pa, 0, 0, 0);
        pa = __builtin_amdgcn_mfma_f32_16x16x32_bf16(aqA[1], bk1, pa, 0, 0, 0);
        pa = __builtin_amdgcn_mfma_f32_16x16x32_bf16(aqA[2], bk2, pa, 0, 0, 0);
        pa = __builtin_amdgcn_mfma_f32_16x16x32_bf16(aqA[3], bk3, pa, 0, 0, 0);
        #pragma unroll
        for (int r = 0; r < 4; ++r) {
          int t = tbA + lg * 4 + r;
          float val = pa[r] * scale * __expf(gv - mlA[r]);
          float w = (s <= t) ? val : 0.f;
          rsA[r] += w;
          plds[wv][0][lg * 4 + r][ns * 16 + li] = (__bf16)w;
        }
      }
      {
        floatx4 pb = (floatx4)(0.f);
        pb = __builtin_amdgcn_mfma_f32_16x16x32_bf16(aqB[0], bk0, pb, 0, 0, 0);
        pb = __builtin_amdgcn_mfma_f32_16x16x32_bf16(aqB[1], bk1, pb, 0, 0, 0);
        pb = __builtin_amdgcn_mfma_f32_16x16x32_bf16(aqB[2], bk2, pb, 0, 0, 0);
        pb = __builtin_amdgcn_mfma_f32_16x16x32_bf16(aqB[3], bk3, pb, 0, 0, 0);
        #pragma unroll
        for (int r = 0; r < 4; ++r) {
          int t = tbB + lg * 4 + r;
          float val = pb[r] * scale * __expf(gv - mlB[r]);
          float w = (s <= t) ? val : 0.f;
          rsB[r] += w;
          plds[wv][1][lg * 4 + r][ns * 16 + li] = (__bf16)w;
        }
      }
    }
    bf16x8 apA0, apA1, apB0, apB1;
    if (actA) {
      apA0 = *(const bf16x8*)&plds[wv][0][li][lg * 8];
      apA1 = *(const bf16x8*)&plds[wv][0][li][32 + lg * 8];
    }
    apB0 = *(const bf16x8*)&plds[wv][1][li][lg * 8];
    apB1 = *(const bf16x8*)&plds[wv][1][li][32 + lg * 8];
    #pragma unroll
    for (int df = 0; df < 8; ++df) {
      bf16x8 bv0 = *(const bf16x8*)&Vs[df * 16 + li][lg * 8];
      bf16x8 bv1 = *(const bf16x8*)&Vs[df * 16 + li][32 + lg * 8];
      if (actA) {
        oA[df] = __builtin_amdgcn_mfma_f32_16x16x32_bf16(apA0, bv0, oA[df], 0, 0, 0);
        oA[df] = __builtin_amdgcn_mfma_f32_16x16x32_bf16(apA1, bv1, oA[df], 0, 0, 0);
      }
      oB[df] = __builtin_amdgcn_mfma_f32_16x16x32_bf16(apB0, bv0, oB[df], 0, 0, 0);
      oB[df] = __builtin_amdgcn_mfma_f32_16x16x32_bf16(apB1, bv1, oB[df], 0, 0, 0);
    }
  }
  // row-sum reduce across the 16 col-lanes
  #pragma unroll
  for (int r = 0; r < 4; ++r) {
    float a = rsA[r], b = rsB[r];
    a += __shfl_xor(a, 1, 64); a += __shfl_xor(a, 2, 64);
    a += __shfl_xor(a, 4, 64); a += __shfl_xor(a, 8, 64);
    b += __shfl_xor(b, 1, 64); b += __shfl_xor(b, 2, 64);
    b += __shfl_xor(b, 4, 64); b += __shfl_xor(b, 8, 64);
    rsA[r] = a; rsB[r] = b;
  }
  // fused epilogue: normalize + GroupNorm(128) + skip*xc + *silu(z), write bf16
  #pragma unroll
  for (int tile = 0; tile < 2; ++tile) {
    int tb = tile == 0 ? tbA : tbB;
    #pragma unroll
    for (int r = 0; r < 4; ++r) {
      float rs = tile == 0 ? rsA[r] : rsB[r];
      float nf = tile == 0 ? nfA[r] : nfB[r];
      float inv = 1.f / (fmaxf(fabsf(rs), nf) + 1e-6f);
      float v8[8], s1 = 0.f, s2 = 0.f;
      #pragma unroll
      for (int df = 0; df < 8; ++df) {
        float v = (tile == 0 ? oA[df][r] : oB[df][r]) * inv;
        v8[df] = v;
        s1 += v;
        s2 += v * v;
      }
      s1 += __shfl_xor(s1, 1, 64); s1 += __shfl_xor(s1, 2, 64);
      s1 += __shfl_xor(s1, 4, 64); s1 += __shfl_xor(s1, 8, 64);
      s2 += __shfl_xor(s2, 1, 64); s2 += __shfl_xor(s2, 2, 64);
      s2 += __shfl_xor(s2, 4, 64); s2 += __shfl_xor(s2, 8, 64);
      float mu = s1 * (1.f / 128.f);
      float var = s2 * (1.f / 128.f) - mu * mu;
      float rq = rsqrtf(var + 1e-5f);
      int t = tb + lg * 4 + r;
      const __bf16* xr = xc + ((size_t)(bb * S + t)) * 512 + hh * 128 + li;
      const __bf16* zr = up + ((size_t)(bb * S + t)) * 1024 + 512 + hh * 128 + li;
      __bf16* od = hd + ((size_t)(bb * S + t)) * 512 + hh * 128 + li;
      #pragma unroll
      for (int df = 0; df < 8; ++df) {
        int c = df * 16 + li;
        float ln = (v8[df] - mu) * rq * glds[c] + blds[c];
        float val = ln + slds[c] * (float)xr[df * 16];
        float z = (float)zr[df * 16];
        float sg = 1.f / (1.f + __expf(-z));
        od[df * 16] = (__bf16)(val * (z * sg));
      }
    }
  }
}

// ---------------- final LN + head ----------------
__global__ __launch_bounds__(256) void final_kernel(
    const float* __restrict__ h, const float* __restrict__ g,
    const float* __restrict__ b, const float* __restrict__ Wf,
    const float* __restrict__ bf, float* __restrict__ out) {
  int bb = blockIdx.x, tid = threadIdx.x;
  size_t row = (size_t)(bb * S + S - 1) * 256;
  __shared__ float red[4];
  float v = h[row + tid];
  float s = wave_sum(v);
  int wid = tid >> 6, lane = tid & 63;
  if (lane == 0) red[wid] = s;
  __syncthreads();
  float mu = (red[0] + red[1] + red[2] + red[3]) * (1.f / 256.f);
  __syncthreads();
  float d = v - mu;
  float s2 = wave_sum(d * d);
  if (lane == 0) red[wid] = s2;
  __syncthreads();
  float var = (red[0] + red[1] + red[2] + red[3]) * (1.f / 256.f);
  float rs = rsqrtf(var + 1e-5f);
  float ln = d * rs * g[tid] + b[tid];
  float p = ln * Wf[tid];
  float psum = wave_sum(p);
  __syncthreads();
  if (lane == 0) red[wid] = psum;
  __syncthreads();
  if (tid == 0) out[bb] = red[0] + red[1] + red[2] + red[3] + bf[0];
}

extern "C" void kernel_launch(void* const* d_in, const int* in_sizes, int n_in,
                              void* d_out, int out_size, void* d_ws, size_t ws_size,
                              hipStream_t stream) {
  const float* x      = (const float*)d_in[0];
  const float* tf     = (const float*)d_in[1];
  const float* Wp     = (const float*)d_in[2];
  const float* bp     = (const float*)d_in[3];
  const float* ln_g   = (const float*)d_in[4];
  const float* ln_b   = (const float*)d_in[5];
  const float* Wup    = (const float*)d_in[6];
  const float* bup    = (const float*)d_in[7];
  const float* conv_w = (const float*)d_in[8];
  const float* conv_b = (const float*)d_in[9];
  const float* Wq     = (const float*)d_in[10];
  const float* Wk     = (const float*)d_in[11];
  const float* Wv     = (const float*)d_in[12];
  const float* Wif    = (const float*)d_in[13];
  const float* bif    = (const float*)d_in[14];
  const float* gn_g   = (const float*)d_in[15];
  const float* gn_b   = (const float*)d_in[16];
  const float* skip   = (const float*)d_in[17];
  const float* Wdown  = (const float*)d_in[18];
  const float* bdown  = (const float*)d_in[19];
  const float* lnf_g  = (const float*)d_in[20];
  const float* lnf_b  = (const float*)d_in[21];
  const float* Wf     = (const float*)d_in[22];
  const float* bf     = (const float*)d_in[23];
  float* out = (float*)d_out;

  float* h     = (float*)d_ws;              // 2,097,152 f32
  float* gates = h + 2097152;               // 65,536 f32
  float* gbuf  = gates + 65536;             // 32,768
  float* Mbuf  = gbuf + 32768;              // 32,768
  float* NFbuf = Mbuf + 32768;              // 32,768
  float* wgbuf = NFbuf + 32768;             // 32,768
  __bf16* hn   = (__bf16*)(wgbuf + 32768);  // 2,097,152 bf16
  __bf16* up   = hn + 2097152;              // 8,388,608
  __bf16* xc   = up + 8388608;              // 4,194,304
  __bf16* qk   = xc + 4194304;              // 8,388,608
  __bf16* vT   = qk + 8388608;              // 4,194,304
  __bf16* hd   = vT + 4194304;              // 4,194,304
  __bf16* WupT   = hd + 4194304;            // 1,048,576
  __bf16* WqkT   = WupT + 1048576;          // 2,097,152
  __bf16* WvT    = WqkT + 2097152;          // 1,048,576
  __bf16* WdownT = WvT + 1048576;           // 524,288

  wtrans_kernel<<<4608, 256, 0, stream>>>(Wup, Wq, Wk, Wv, Wdown,
                                          WupT, WqkT, WvT, WdownT);
  wgprep_kernel<<<1024, 256, 0, stream>>>(Wq, Wk, Wv, Wif, wgbuf);
  embed_kernel<<<8192, 256, 0, stream>>>(x, tf, Wp, bp, ln_g, ln_b, h, hn);
  for (int l = 0; l < NLAYER; ++l) {
    if (l > 0)
      ln256_kernel<<<8192, 256, 0, stream>>>(h, ln_g + l * 256, ln_b + l * 256, hn);
    hgemm<1, 0><<<dim3(8, 64), 256, 0, stream>>>(
        hn, 256, WupT + (size_t)l * 262144, 256, bup + l * 1024, up, 1024);
    conv_silu_kernel<<<2048, 256, 0, stream>>>(up, conv_w + l * 2048, conv_b + l * 512,
                                               wgbuf + l * 8192, bif + l * 8, xc, gates);
    scan_kernel<<<32, 64, 0, stream>>>(gates, gbuf, Mbuf, NFbuf);
    hgemm<1, 0><<<dim3(8, 64), 256, 0, stream>>>(
        xc, 512, WqkT + (size_t)l * 524288, 512, nullptr, qk, 1024);
    hgemm<2, 0><<<dim3(4, 64), 256, 0, stream>>>(
        up, 1024, WvT + (size_t)l * 262144, 512, nullptr, vT, 0);
    attn_kernel<<<dim3(8, 32), 256, 0, stream>>>(
        qk, vT, gbuf, Mbuf, NFbuf, gn_g + l * 512, gn_b + l * 512, skip + l * 512,
        xc, up, hd);
    hgemm<0, 1><<<dim3(2, 64), 256, 0, stream>>>(
        hd, 512, WdownT + (size_t)l * 131072, 512, bdown + l * 256, h, 256);
  }
  final_kernel<<<8, 256, 0, stream>>>(h, lnf_g, lnf_b, Wf, bf, out);
}